// Round 3
// baseline (3036.674 us; speedup 1.0000x reference)
//
#include <hip/hip_runtime.h>

// ---------------------------------------------------------------------------
// Two-layer tanh RNN — fully fused persistent kernel with software pipeline.
// B=64, T=512, H=512, I=128, W_OUT=32 (fp32 in/out; f16-pair internal, fp32 acc).
//
// 256 WGs x 256 threads, all co-resident (1/CU). WG = (batch-group g of 2
// batches, row-group wgr of 64 rows). All 8 row-WGs of a group share one XCD
// (block index remap). Each WG holds BOTH layers' weight slices pinned in
// VGPRs (80 + 128 pairs/lane). Per iteration i:
//   A : layer-0 step i  (x(i)|h0(i-1)) -> post h0(i)      [tagged ring, 4-deep]
//   B : gather h1(i-2)  (RTT elapsed: posted last iter)
//   B': layer-1 step i-1 (h0(i-1)|h1(i-2)) -> post h1(i-1)
//   C : gather h0(i)    (RTT overlapped by B/B'), prefetch x(i+1)
// Exchange: 64-bit {tag|f16pair} atoms; dual store (plain->local L2, sc1->MALL);
// poll alternates sc0 (local-XCD L2 fast path) and agent-scope (correct under
// any WG->XCD mapping). FC epilogue fused into row-group-0 WGs.
// ---------------------------------------------------------------------------

#define T_STEPS 512
#define NBATCH  64

typedef _Float16 half2v __attribute__((ext_vector_type(2)));

__device__ __forceinline__ unsigned pack2(float a, float b) {
    _Float16 fa = (_Float16)a, fb = (_Float16)b;
    unsigned short ua = __builtin_bit_cast(unsigned short, fa);
    unsigned short ub = __builtin_bit_cast(unsigned short, fb);
    return (unsigned)ua | ((unsigned)ub << 16);
}

__device__ __forceinline__ float dot2acc(unsigned w, unsigned h, float acc) {
#if __has_builtin(__builtin_amdgcn_fdot2)
    return __builtin_amdgcn_fdot2(__builtin_bit_cast(half2v, w),
                                  __builtin_bit_cast(half2v, h), acc, false);
#else
    half2v wv = __builtin_bit_cast(half2v, w);
    half2v hv = __builtin_bit_cast(half2v, h);
    acc = fmaf((float)wv.x, (float)hv.x, acc);
    return fmaf((float)wv.y, (float)hv.y, acc);
#endif
}

__device__ __forceinline__ float fast_tanh(float xv) {
    // tanh(x) = 1 - 2/(e^{2x}+1); saturates correctly at +-inf.
    float e2 = __builtin_amdgcn_exp2f(xv * 2.885390082f);
    return 1.f - 2.f * __builtin_amdgcn_rcpf(e2 + 1.f);
}

// local-XCD-L2 load (bypass L1 only). Fast path for same-XCD exchange.
__device__ __forceinline__ unsigned long long ld_l2(const unsigned long long* p) {
    unsigned long long v;
    asm volatile("global_load_dwordx2 %0, %1, off sc0\n\t"
                 "s_waitcnt vmcnt(0)"
                 : "=v"(v) : "v"(p) : "memory");
    return v;
}

__device__ __forceinline__ void post_pair(unsigned long long* p, unsigned long long atom) {
    *(volatile unsigned long long*)p = atom;   // local L2 (same-XCD consumers)
    __hip_atomic_store(p, atom, __ATOMIC_RELAXED, __HIP_MEMORY_SCOPE_AGENT); // MALL
}

__device__ __forceinline__ unsigned poll_pair(unsigned long long* p, unsigned tag,
                                              long& budget) {
    unsigned long long v = ld_l2(p);
    if ((unsigned)(v >> 32) == tag) return (unsigned)v;
    for (;;) {
        v = __hip_atomic_load(p, __ATOMIC_RELAXED, __HIP_MEMORY_SCOPE_AGENT);
        if ((unsigned)(v >> 32) == tag) break;
        v = ld_l2(p);
        if ((unsigned)(v >> 32) == tag) break;
        if (--budget < 0) break;               // hang-bailout
    }
    return (unsigned)v;
}

// Packed-weight layouts [wgr<8][j<P][lane<256] (same as prior rounds).
#define N0 (8 * 80 * 256)
#define N1 (8 * 128 * 256)

__global__ void init_pack(const float* __restrict__ Wih0, const float* __restrict__ Whh0,
                          const float* __restrict__ Wih1, const float* __restrict__ Whh1,
                          unsigned* __restrict__ wp0, unsigned* __restrict__ wp1) {
    int gid = blockIdx.x * 256 + threadIdx.x;
    if (gid < N0) {
        int L = gid & 255; int j = (gid >> 8) % 80; int wg = (gid >> 8) / 80;
        int r = wg * 64 + (L >> 2); int c = L & 3; int k = c * 160 + 2 * j;
        float w0 = (k < 128) ? Wih0[r * 128 + k]     : Whh0[r * 512 + (k - 128)];
        float w1 = (k + 1 < 128) ? Wih0[r * 128 + k + 1] : Whh0[r * 512 + (k - 127)];
        wp0[gid] = pack2(w0, w1);
    } else {
        int g2 = gid - N0;
        if (g2 < N1) {
            int L = g2 & 255; int j = (g2 >> 8) % 128; int wg = (g2 >> 8) / 128;
            int r = wg * 64 + (L >> 2); int c = L & 3; int k = c * 256 + 2 * j;
            float w0 = (k < 512) ? Wih1[r * 512 + k]     : Whh1[r * 512 + (k - 512)];
            float w1 = (k + 1 < 512) ? Wih1[r * 512 + k + 1] : Whh1[r * 512 + (k - 511)];
            wp1[g2] = pack2(w0, w1);
        }
    }
}

__global__ __launch_bounds__(256, 1)
void rnn_fused(const float* __restrict__ x, const float* __restrict__ noise,
               const unsigned* __restrict__ wp0, const unsigned* __restrict__ wp1,
               const float* __restrict__ bih0, const float* __restrict__ bhh0,
               const float* __restrict__ bih1, const float* __restrict__ bhh1,
               const float* __restrict__ fcw, const float* __restrict__ fcb,
               unsigned long long* __restrict__ hbuf0,
               unsigned long long* __restrict__ hbuf1,
               float* __restrict__ out) {
    const int L    = threadIdx.x;
    const int xcd  = blockIdx.x & 7;
    const int slot = blockIdx.x >> 3;            // 0..31 within XCD
    const int g    = xcd * 4 + (slot & 3);       // batch-group 0..31 (XCD-local)
    const int wgr  = slot >> 2;                  // row-group 0..7
    const int b0   = g * 2;

    const int c    = L & 3;                      // k-chunk
    const int rloc = L >> 2;
    const int r    = wgr * 64 + rloc;            // owned row (both layers)

    // --- both layers' weight slices, pinned in VGPRs (208 regs) ---
    unsigned w0[80], w1[128];
#pragma unroll
    for (int j = 0; j < 80; ++j) {
        w0[j] = wp0[(wgr * 80 + j) * 256 + L];
        asm volatile("" : "+v"(w0[j]));
    }
#pragma unroll
    for (int j = 0; j < 128; ++j) {
        w1[j] = wp1[(wgr * 128 + j) * 256 + L];
        asm volatile("" : "+v"(w1[j]));
    }

    const float cb0 = bih0[r] + bhh0[r];
    const float cb1 = bih1[r] + bhh1[r];

    // LDS: layer-0 input (x|h0), layer-1 h0-part, layer-1 h1-part (parity dbuf)
    __shared__ __align__(16) unsigned l0s[2][4][84];        // [batch][chunk][pair]
    __shared__ __align__(16) unsigned h0s[2][2][132];       // [batch][chunk][pair]
    __shared__ __align__(16) unsigned h1s[2][2][2][132];    // [par][batch][chunk][pair]
    __shared__ float hs[2][512];                            // FC epilogue
    __shared__ float part[2][256];

    for (int i2 = L; i2 < 2 * 4 * 84; i2 += 256) ((unsigned*)l0s)[i2] = 0u;
    for (int i2 = L; i2 < 2 * 2 * 132; i2 += 256) ((unsigned*)h0s)[i2] = 0u;
    for (int i2 = L; i2 < 2 * 2 * 2 * 132; i2 += 256) ((unsigned*)h1s)[i2] = 0u;
    __syncthreads();
    if (L < 128) {                                // x(0)
        int bb = L >> 6, j = L & 63;
        float2 xf0 = *(const float2*)(x + ((size_t)(b0 + bb) * T_STEPS) * 128 + 2 * j);
        l0s[bb][0][j] = pack2(xf0.x, xf0.y);
    }
    __syncthreads();

    long budget = 100000000L;
    float h0new[2];

    for (int i = 0; i <= T_STEPS; ++i) {
        const bool doA = (i < T_STEPS);
        const bool doB = (i >= 1);

        // ---- A: layer-0 step i ----
        if (doA) {
#pragma unroll
            for (int bb = 0; bb < 2; ++bb) {
                const uint4* hq = (const uint4*)(&l0s[bb][c][0]);
                float a0 = 0.f, a1 = 0.f, a2 = 0.f, a3 = 0.f;
#pragma unroll
                for (int jj = 0; jj < 20; ++jj) {
                    uint4 hp = hq[jj];
                    a0 = dot2acc(w0[4 * jj + 0], hp.x, a0);
                    a1 = dot2acc(w0[4 * jj + 1], hp.y, a1);
                    a2 = dot2acc(w0[4 * jj + 2], hp.z, a2);
                    a3 = dot2acc(w0[4 * jj + 3], hp.w, a3);
                }
                float acc = (a0 + a1) + (a2 + a3);
                acc += __shfl_xor(acc, 1);
                acc += __shfl_xor(acc, 2);
                float nz = noise[(((size_t)(b0 + bb) * T_STEPS + i) * 2 + 0) * 512 + r];
                h0new[bb] = fast_tanh(acc + cb0 + nz);
            }
#pragma unroll
            for (int bb = 0; bb < 2; ++bb) {     // post h0(i), tag i+1, slot i&3
                float hnb = __shfl_down(h0new[bb], 4);
                if ((L & 7) == 0) {
                    unsigned pv = pack2(h0new[bb], hnb);
                    unsigned long long atom =
                        ((unsigned long long)(unsigned)(i + 1) << 32) | (unsigned long long)pv;
                    post_pair(&hbuf0[((size_t)(i & 3) * NBATCH + (b0 + bb)) * 256 + (r >> 1)], atom);
                }
            }
        }

        // ---- B: gather h1(i-2) (tag i-1, slot (i-2)&3) ----
        unsigned h1g[2];
        if (i >= 2) {
#pragma unroll
            for (int bb = 0; bb < 2; ++bb)
                h1g[bb] = poll_pair(
                    &hbuf1[((size_t)((i - 2) & 3) * NBATCH + (b0 + bb)) * 256 + L],
                    (unsigned)(i - 1), budget);
            // scatter into parity slot i&1 (last read of this slot was iter i-2)
#pragma unroll
            for (int bb = 0; bb < 2; ++bb)
                h1s[i & 1][bb][L >> 7][L & 127] = h1g[bb];
        }
        __syncthreads();   // h1 scatter visible; A's l0s reads done

        // ---- B': layer-1 step i-1, post h1(i-1) ----
        if (doB) {
            const int par = i & 1;               // (i-2)&1 == i&1
#pragma unroll
            for (int bb = 0; bb < 2; ++bb) {
                const unsigned* base = (c < 2) ? &h0s[bb][c][0] : &h1s[par][bb][c - 2][0];
                const uint4* hq = (const uint4*)base;
                float a0 = 0.f, a1 = 0.f, a2 = 0.f, a3 = 0.f;
#pragma unroll
                for (int jj = 0; jj < 32; ++jj) {
                    uint4 hp = hq[jj];
                    a0 = dot2acc(w1[4 * jj + 0], hp.x, a0);
                    a1 = dot2acc(w1[4 * jj + 1], hp.y, a1);
                    a2 = dot2acc(w1[4 * jj + 2], hp.z, a2);
                    a3 = dot2acc(w1[4 * jj + 3], hp.w, a3);
                }
                float acc = (a0 + a1) + (a2 + a3);
                acc += __shfl_xor(acc, 1);
                acc += __shfl_xor(acc, 2);
                float nz = noise[(((size_t)(b0 + bb) * T_STEPS + (i - 1)) * 2 + 1) * 512 + r];
                float h1new = fast_tanh(acc + cb1 + nz);
                float hnb = __shfl_down(h1new, 4);
                if ((L & 7) == 0) {              // post h1(i-1), tag i, slot (i-1)&3
                    unsigned pv = pack2(h1new, hnb);
                    unsigned long long atom =
                        ((unsigned long long)(unsigned)i << 32) | (unsigned long long)pv;
                    post_pair(&hbuf1[((size_t)((i - 1) & 3) * NBATCH + (b0 + bb)) * 256 + (r >> 1)], atom);
                }
            }
        }

        // ---- C: gather h0(i) (RTT overlapped by B/B'), prefetch x(i+1) ----
        unsigned h0g[2];
        float2 xf = make_float2(0.f, 0.f);
        if (doA) {
            if (L < 128 && (i + 1) < T_STEPS) {
                int bb = L >> 6, j = L & 63;
                xf = *(const float2*)(x + ((size_t)(b0 + bb) * T_STEPS + (i + 1)) * 128 + 2 * j);
            }
#pragma unroll
            for (int bb = 0; bb < 2; ++bb)
                h0g[bb] = poll_pair(
                    &hbuf0[((size_t)(i & 3) * NBATCH + (b0 + bb)) * 256 + L],
                    (unsigned)(i + 1), budget);
        }
        __syncthreads();   // B' h0s/h1s reads done before overwrite
        if (doA) {
#pragma unroll
            for (int bb = 0; bb < 2; ++bb) {
                int q = 64 + L;                  // layer-0 region pair index
                l0s[bb][q / 80][q % 80] = h0g[bb];
                h0s[bb][L >> 7][L & 127] = h0g[bb];
            }
            if (L < 128) {
                int bb = L >> 6, j = L & 63;
                l0s[bb][0][j] = pack2(xf.x, xf.y);
            }
        }
        __syncthreads();   // scatters visible for next iteration's A
    }

    // ---- FC epilogue: row-group-0 WGs compute out = h1(T-1) @ fc_w^T + fc_b ----
    if (wgr == 0) {
#pragma unroll
        for (int bb = 0; bb < 2; ++bb) {
            unsigned pv = poll_pair(
                &hbuf1[((size_t)((T_STEPS - 1) & 3) * NBATCH + (b0 + bb)) * 256 + L],
                (unsigned)T_STEPS, budget);
            half2v hv2 = __builtin_bit_cast(half2v, pv);
            hs[bb][2 * L]     = (float)hv2.x;
            hs[bb][2 * L + 1] = (float)hv2.y;
        }
        __syncthreads();
        const int o = L & 31, seg = L >> 5;      // 32 outputs x 8 k-segments
#pragma unroll
        for (int bb = 0; bb < 2; ++bb) {
            const float* wr = fcw + o * 512 + seg * 64;
            const float* hr = &hs[bb][seg * 64];
            float a = 0.f;
#pragma unroll 16
            for (int k = 0; k < 64; ++k) a = fmaf(wr[k], hr[k], a);
            part[bb][L] = a;
        }
        __syncthreads();
        if (L < 64) {
            int bb = L >> 5, oo = L & 31;
            float s = fcb[oo];
#pragma unroll
            for (int sgi = 0; sgi < 8; ++sgi) s += part[bb][sgi * 32 + oo];
            out[(b0 + bb) * 32 + oo] = s;
        }
    }
}

extern "C" void kernel_launch(void* const* d_in, const int* in_sizes, int n_in,
                              void* d_out, int out_size, void* d_ws, size_t ws_size,
                              hipStream_t stream) {
    const float* x     = (const float*)d_in[0];
    const float* noise = (const float*)d_in[1];
    const float* Wih0  = (const float*)d_in[2];
    const float* Wih1  = (const float*)d_in[3];
    const float* Whh0  = (const float*)d_in[4];
    const float* Whh1  = (const float*)d_in[5];
    const float* bih0  = (const float*)d_in[6];
    const float* bih1  = (const float*)d_in[7];
    const float* bhh0  = (const float*)d_in[8];
    const float* bhh1  = (const float*)d_in[9];
    const float* fcw   = (const float*)d_in[10];
    const float* fcb   = (const float*)d_in[11];
    float* out = (float*)d_out;

    char* ws = (char*)d_ws;
    size_t o = 0;
    unsigned* wp0 = (unsigned*)(ws + o); o += (size_t)N0 * 4;                   // 640 KB
    unsigned* wp1 = (unsigned*)(ws + o); o += (size_t)N1 * 4;                   // 1 MB
    unsigned long long* hb0 = (unsigned long long*)(ws + o); o += (size_t)4 * NBATCH * 256 * 8; // 512 KB
    unsigned long long* hb1 = (unsigned long long*)(ws + o); o += (size_t)4 * NBATCH * 256 * 8; // 512 KB

    const int initBlocks = (N0 + N1 + 255) / 256;
    init_pack<<<initBlocks, 256, 0, stream>>>(Wih0, Whh0, Wih1, Whh1, wp0, wp1);
    rnn_fused<<<256, 256, 0, stream>>>(x, noise, wp0, wp1, bih0, bhh0, bih1, bhh1,
                                       fcw, fcb, hb0, hb1, out);
}

// Round 4
// 1661.026 us; speedup vs baseline: 1.8282x; 1.8282x over previous
//
#include <hip/hip_runtime.h>

// ---------------------------------------------------------------------------
// Two-layer tanh RNN — concurrent-layer persistent kernel (grid-axis fusion).
// B=64, T=512, H=512, I=128, W_OUT=32. fp32 in/out, f16-pair internal, fp32 acc.
//
// One dispatch, 512 WGs x 256 (launch_bounds(256,2) => all co-resident):
//   layer = blockIdx&1; 256 WGs per layer = 8 row-groups x 32 batch-pairs.
//   Each WG: round-2 structure (lane owns row r=wgr*64+L/4, chunk c=L&3,
//   weights pinned in regs, h broadcast from LDS, dot2 fp32 acc) x 2 batches.
// Exchange: 64-bit {tag|f16pair} atoms, RELAXED agent scope, no fences.
//   hbuf0: 256-step ring (layer-0 posts; layer-0 self-gather + layer-1 gather;
//          depth >> max layer lead (~67 steps) => overwrite-race-free).
//   hbuf1: 4-step ring (layer-1 self-recurrence, as round 2).
// Layer-1 trails layer-0 by ~1 step; total ~= T*step instead of 2*T*step.
// FC epilogue fused into layer-1 wgr==0 WGs.
// ---------------------------------------------------------------------------

#define T_STEPS 512
#define NBATCH  64
#define DRING   256

typedef _Float16 half2v __attribute__((ext_vector_type(2)));

__device__ __forceinline__ unsigned pack2(float a, float b) {
    _Float16 fa = (_Float16)a, fb = (_Float16)b;
    unsigned short ua = __builtin_bit_cast(unsigned short, fa);
    unsigned short ub = __builtin_bit_cast(unsigned short, fb);
    return (unsigned)ua | ((unsigned)ub << 16);
}

__device__ __forceinline__ float dot2acc(unsigned w, unsigned h, float acc) {
#if __has_builtin(__builtin_amdgcn_fdot2)
    return __builtin_amdgcn_fdot2(__builtin_bit_cast(half2v, w),
                                  __builtin_bit_cast(half2v, h), acc, false);
#else
    half2v wv = __builtin_bit_cast(half2v, w);
    half2v hv = __builtin_bit_cast(half2v, h);
    acc = fmaf((float)wv.x, (float)hv.x, acc);
    return fmaf((float)wv.y, (float)hv.y, acc);
#endif
}

__device__ __forceinline__ float fast_tanh(float xv) {
    float e2 = __builtin_amdgcn_exp2f(xv * 2.885390082f);
    return 1.f - 2.f * __builtin_amdgcn_rcpf(e2 + 1.f);
}

// Poll N tagged atoms concurrently (overlapped RTTs), relaxed agent scope.
template <int N>
__device__ __forceinline__ void pollN(unsigned long long* const (&p)[N],
                                      const unsigned (&tag)[N],
                                      unsigned (&res)[N], long& budget) {
    bool done[N];
#pragma unroll
    for (int i = 0; i < N; ++i) done[i] = false;
    int remaining = N;
    while (remaining > 0 && budget > 0) {
        unsigned long long v[N];
#pragma unroll
        for (int i = 0; i < N; ++i)
            if (!done[i])
                v[i] = __hip_atomic_load(p[i], __ATOMIC_RELAXED, __HIP_MEMORY_SCOPE_AGENT);
#pragma unroll
        for (int i = 0; i < N; ++i)
            if (!done[i] && (unsigned)(v[i] >> 32) == tag[i]) {
                res[i] = (unsigned)v[i]; done[i] = true; --remaining;
            }
        --budget;
    }
}

// Packed-weight layouts [wgr<8][j<P][lane<256] (as prior rounds).
#define N0 (8 * 80 * 256)
#define N1 (8 * 128 * 256)

__global__ void init_pack(const float* __restrict__ Wih0, const float* __restrict__ Whh0,
                          const float* __restrict__ Wih1, const float* __restrict__ Whh1,
                          unsigned* __restrict__ wp0, unsigned* __restrict__ wp1) {
    int gid = blockIdx.x * 256 + threadIdx.x;
    if (gid < N0) {
        int L = gid & 255; int j = (gid >> 8) % 80; int wg = (gid >> 8) / 80;
        int r = wg * 64 + (L >> 2); int c = L & 3; int k = c * 160 + 2 * j;
        float w0 = (k < 128) ? Wih0[r * 128 + k]     : Whh0[r * 512 + (k - 128)];
        float w1 = (k + 1 < 128) ? Wih0[r * 128 + k + 1] : Whh0[r * 512 + (k - 127)];
        wp0[gid] = pack2(w0, w1);
    } else {
        int g2 = gid - N0;
        if (g2 < N1) {
            int L = g2 & 255; int j = (g2 >> 8) % 128; int wg = (g2 >> 8) / 128;
            int r = wg * 64 + (L >> 2); int c = L & 3; int k = c * 256 + 2 * j;
            float w0 = (k < 512) ? Wih1[r * 512 + k]     : Whh1[r * 512 + (k - 512)];
            float w1 = (k + 1 < 512) ? Wih1[r * 512 + k + 1] : Whh1[r * 512 + (k - 511)];
            wp1[g2] = pack2(w0, w1);
        }
    }
}

// PW: f16-pairs per lane (80 or 128). KIN: non-recurrent width (128 or 512).
template <int PW, int KIN, int LAYER>
__device__ __forceinline__ void run_layer(
    int b0, int wgr, int L,
    const float* __restrict__ x, const float* __restrict__ noise,
    const unsigned* __restrict__ wpack,
    const float* __restrict__ bih, const float* __restrict__ bhh,
    unsigned long long* __restrict__ hbuf0,
    unsigned long long* __restrict__ hbuf1,
    const float* __restrict__ fcw, const float* __restrict__ fcb,
    float* __restrict__ out) {
    constexpr int CH = PW + 4;           // LDS chunk stride (16B-aligned: (PW+4)*4 % 16 == 0)
    const int c = L & 3;
    const int r = wgr * 64 + (L >> 2);

    unsigned wreg[PW];
#pragma unroll
    for (int j = 0; j < PW; ++j) {
        wreg[j] = wpack[(wgr * PW + j) * 256 + L];
        asm volatile("" : "+v"(wreg[j]));
    }

    const float cb = bih[r] + bhh[r];

    __shared__ __align__(16) unsigned hv[2][4][CH];
    for (int i = L; i < 2 * 4 * CH; i += 256) ((unsigned*)hv)[i] = 0u;  // h(-1)=0
    __syncthreads();

    long budget = 2000000000L;           // hang bailout only

    // t=0 input region
    if constexpr (LAYER == 0) {
        if (L < 128) {
            int bb = L >> 6, j = L & 63;
            float2 xf = *(const float2*)(x + ((size_t)(b0 + bb) * T_STEPS) * 128 + 2 * j);
            hv[bb][j / PW][j % PW] = pack2(xf.x, xf.y);
        }
    } else {
        unsigned long long* p[2]; unsigned tg[2], res[2];
#pragma unroll
        for (int bb = 0; bb < 2; ++bb) {
            p[bb] = &hbuf0[((size_t)0 * NBATCH + (b0 + bb)) * 256 + L];
            tg[bb] = 1u;
        }
        pollN<2>(p, tg, res, budget);
#pragma unroll
        for (int bb = 0; bb < 2; ++bb) hv[bb][L >> 7][L & 127] = res[bb];
    }
    __syncthreads();

    float nz[2];
#pragma unroll
    for (int bb = 0; bb < 2; ++bb)
        nz[bb] = noise[(((size_t)(b0 + bb) * T_STEPS) * 2 + LAYER) * 512 + r];

    for (int t = 0; t < T_STEPS; ++t) {
        float hnew[2];
#pragma unroll
        for (int bb = 0; bb < 2; ++bb) {
            const uint4* hq = (const uint4*)(&hv[bb][c][0]);
            float a0 = 0.f, a1 = 0.f, a2 = 0.f, a3 = 0.f;
#pragma unroll
            for (int jj = 0; jj < PW / 4; ++jj) {
                uint4 hp = hq[jj];
                a0 = dot2acc(wreg[4 * jj + 0], hp.x, a0);
                a1 = dot2acc(wreg[4 * jj + 1], hp.y, a1);
                a2 = dot2acc(wreg[4 * jj + 2], hp.z, a2);
                a3 = dot2acc(wreg[4 * jj + 3], hp.w, a3);
            }
            float acc = (a0 + a1) + (a2 + a3);
            acc += __shfl_xor(acc, 1);
            acc += __shfl_xor(acc, 2);
            hnew[bb] = fast_tanh(acc + cb + nz[bb]);
        }
        // post h(t), tag t+1
#pragma unroll
        for (int bb = 0; bb < 2; ++bb) {
            float hnb = __shfl_down(hnew[bb], 4);
            if ((L & 7) == 0) {
                unsigned pv = pack2(hnew[bb], hnb);
                unsigned long long atom =
                    ((unsigned long long)(unsigned)(t + 1) << 32) | (unsigned long long)pv;
                if constexpr (LAYER == 0)
                    __hip_atomic_store(
                        &hbuf0[((size_t)(t & (DRING - 1)) * NBATCH + (b0 + bb)) * 256 + (r >> 1)],
                        atom, __ATOMIC_RELAXED, __HIP_MEMORY_SCOPE_AGENT);
                else
                    __hip_atomic_store(
                        &hbuf1[((size_t)(t & 3) * NBATCH + (b0 + bb)) * 256 + (r >> 1)],
                        atom, __ATOMIC_RELAXED, __HIP_MEMORY_SCOPE_AGENT);
            }
        }
        if (t == T_STEPS - 1) break;

        // prefetch next-step inputs while stores fly
        float2 xf;
        if constexpr (LAYER == 0) {
            if (L < 128) {
                int bb = L >> 6, j = L & 63;
                xf = *(const float2*)(x + ((size_t)(b0 + bb) * T_STEPS + (t + 1)) * 128 + 2 * j);
            }
        }
#pragma unroll
        for (int bb = 0; bb < 2; ++bb)
            nz[bb] = noise[(((size_t)(b0 + bb) * T_STEPS + (t + 1)) * 2 + LAYER) * 512 + r];

        __syncthreads();                 // this step's hv reads complete

        if constexpr (LAYER == 0) {
            unsigned long long* p[2]; unsigned tg[2], res[2];
#pragma unroll
            for (int bb = 0; bb < 2; ++bb) {
                p[bb] = &hbuf0[((size_t)(t & (DRING - 1)) * NBATCH + (b0 + bb)) * 256 + L];
                tg[bb] = (unsigned)(t + 1);
            }
            pollN<2>(p, tg, res, budget);
#pragma unroll
            for (int bb = 0; bb < 2; ++bb) {
                int q = 64 + L;                          // recurrent pair index
                hv[bb][q / PW][q % PW] = res[bb];
            }
            if (L < 128) {
                int bb = L >> 6, j = L & 63;
                hv[bb][j / PW][j % PW] = pack2(xf.x, xf.y);
            }
        } else {
            unsigned long long* p[4]; unsigned tg[4], res[4];
#pragma unroll
            for (int bb = 0; bb < 2; ++bb) {
                p[bb] = &hbuf1[((size_t)(t & 3) * NBATCH + (b0 + bb)) * 256 + L];
                tg[bb] = (unsigned)(t + 1);              // h1(t) self-recurrence
                p[2 + bb] = &hbuf0[((size_t)((t + 1) & (DRING - 1)) * NBATCH + (b0 + bb)) * 256 + L];
                tg[2 + bb] = (unsigned)(t + 2);          // h0(t+1) from layer-0
            }
            pollN<4>(p, tg, res, budget);
#pragma unroll
            for (int bb = 0; bb < 2; ++bb) {
                int q = 256 + L;                         // h1 pairs -> chunks 2,3
                hv[bb][q >> 7][q & 127] = res[bb];
                hv[bb][L >> 7][L & 127] = res[2 + bb];   // h0 pairs -> chunks 0,1
            }
        }
        __syncthreads();
    }

    if constexpr (LAYER == 1) {
        __shared__ float hs[2][512];
        __shared__ float part[2][256];
        if (wgr == 0) {                  // FC epilogue: out = h1(T-1) @ fc_w^T + fc_b
            unsigned long long* p[2]; unsigned tg[2], res[2];
#pragma unroll
            for (int bb = 0; bb < 2; ++bb) {
                p[bb] = &hbuf1[((size_t)((T_STEPS - 1) & 3) * NBATCH + (b0 + bb)) * 256 + L];
                tg[bb] = (unsigned)T_STEPS;
            }
            pollN<2>(p, tg, res, budget);
#pragma unroll
            for (int bb = 0; bb < 2; ++bb) {
                half2v h2 = __builtin_bit_cast(half2v, res[bb]);
                hs[bb][2 * L] = (float)h2.x; hs[bb][2 * L + 1] = (float)h2.y;
            }
            __syncthreads();
            const int o = L & 31, seg = L >> 5;          // 32 outputs x 8 k-segments
#pragma unroll
            for (int bb = 0; bb < 2; ++bb) {
                const float* wr = fcw + o * 512 + seg * 64;
                const float* hr = &hs[bb][seg * 64];
                float a = 0.f;
#pragma unroll 16
                for (int k = 0; k < 64; ++k) a = fmaf(wr[k], hr[k], a);
                part[bb][L] = a;
            }
            __syncthreads();
            if (L < 64) {
                int bb = L >> 5, oo = L & 31;
                float s = fcb[oo];
#pragma unroll
                for (int sgi = 0; sgi < 8; ++sgi) s += part[bb][sgi * 32 + oo];
                out[(b0 + bb) * 32 + oo] = s;
            }
        }
    }
}

__global__ __launch_bounds__(256, 2)
void rnn_dual(const float* __restrict__ x, const float* __restrict__ noise,
              const unsigned* __restrict__ wp0, const unsigned* __restrict__ wp1,
              const float* __restrict__ bih0, const float* __restrict__ bhh0,
              const float* __restrict__ bih1, const float* __restrict__ bhh1,
              const float* __restrict__ fcw, const float* __restrict__ fcb,
              unsigned long long* __restrict__ hbuf0,
              unsigned long long* __restrict__ hbuf1,
              float* __restrict__ out) {
    const int L = threadIdx.x;
    const int gid = blockIdx.x;
    const int layer = gid & 1;           // XCD = (2g+layer)%8 under rr dispatch:
    const int rest = gid >> 1;           //   all 8 row-WGs of (g,layer) share an XCD
    const int g = rest & 31;
    const int wgr = rest >> 5;
    const int b0 = g * 2;
    if (layer == 0)
        run_layer<80, 128, 0>(b0, wgr, L, x, noise, wp0, bih0, bhh0,
                              hbuf0, hbuf1, nullptr, nullptr, nullptr);
    else
        run_layer<128, 512, 1>(b0, wgr, L, x, noise, wp1, bih1, bhh1,
                               hbuf0, hbuf1, fcw, fcb, out);
}

extern "C" void kernel_launch(void* const* d_in, const int* in_sizes, int n_in,
                              void* d_out, int out_size, void* d_ws, size_t ws_size,
                              hipStream_t stream) {
    const float* x     = (const float*)d_in[0];
    const float* noise = (const float*)d_in[1];
    const float* Wih0  = (const float*)d_in[2];
    const float* Wih1  = (const float*)d_in[3];
    const float* Whh0  = (const float*)d_in[4];
    const float* Whh1  = (const float*)d_in[5];
    const float* bih0  = (const float*)d_in[6];
    const float* bih1  = (const float*)d_in[7];
    const float* bhh0  = (const float*)d_in[8];
    const float* bhh1  = (const float*)d_in[9];
    const float* fcw   = (const float*)d_in[10];
    const float* fcb   = (const float*)d_in[11];
    float* out = (float*)d_out;

    char* ws = (char*)d_ws;
    size_t o = 0;
    unsigned* wp0 = (unsigned*)(ws + o); o += (size_t)N0 * 4;   // 640 KB
    unsigned* wp1 = (unsigned*)(ws + o); o += (size_t)N1 * 4;   // 1 MB
    unsigned long long* hb0 = (unsigned long long*)(ws + o);
    o += (size_t)DRING * NBATCH * 256 * 8;                      // 33.5 MB ring
    unsigned long long* hb1 = (unsigned long long*)(ws + o);
    o += (size_t)4 * NBATCH * 256 * 8;                          // 512 KB ring

    const int initBlocks = (N0 + N1 + 255) / 256;
    init_pack<<<initBlocks, 256, 0, stream>>>(Wih0, Whh0, Wih1, Whh1, wp0, wp1);
    rnn_dual<<<512, 256, 0, stream>>>(x, noise, wp0, wp1, bih0, bhh0, bih1, bhh1,
                                      fcw, fcb, hb0, hb1, out);
}